// Round 7
// baseline (5802.549 us; speedup 1.0000x reference)
//
#include <hip/hip_runtime.h>
#include <hip/hip_bf16.h>

// LSTM DynamicRNN: B=128, T=512, D=256, H=512.
// Round 10 = Round-9 (rotating h-planes in `out`, L2-routed consumer loads)
// + two defensive fixes for the pre-run cache-state hazard that likely
// killed Round 9's container:
//   1. ONE acquire fence (buffer_inv) BEFORE the main loop: drops any
//      stale/dirty lines over our exchange planes left by the harness's
//      reset()/verify activity in other XCDs' L2s. Once per kernel
//      (~1 us), unlike Round-5's fatal per-step fence.
//   2. Consumer h loads use sc0 (L1-bypass, L2-CACHING KEPT) so a per-CU
//      L1 relic can never be served; the cross-block L2 reuse that
//      motivates the design is untouched.
// In-run coherence needs no fences: planes are written once (sc0 sc1
// write-through, vmcnt-acked before flag publish) and first-touched by
// consumers only after flag-detect; L1/L2 are demand-fill.
//
// Design recap (R9): producer h-publish IS the out[b][t][:] store; hbuf
// deleted. fp32 planes cost 2x bytes => nt-twin dedup: twins load disjoint
// 8-ks halves, convert with v_cvt_pk_bf16_f32 (RNE == f2bf_bits numerics),
// exchange A-frags via LDS (+1 barrier). __launch_bounds__(512): 128
// blocks on 256 CUs never co-schedule, the old (512,2) VGPR cap of 128
// was pure pessimization.

#define B_   128
#define T_   512
#define D_   256
#define H_   512
#define G4_  2048   // 4*H
#define NBLK 128
#define KH   16     // h-part k-steps (K=512)
#define KX   8      // x-part k-steps (K=256)
#define XROW 264    // 256 + 8 pad (shorts) per staged x row

typedef __attribute__((ext_vector_type(8))) short short8;
typedef __attribute__((ext_vector_type(4))) short short4v;
typedef __attribute__((ext_vector_type(4))) float float4v;
typedef __attribute__((ext_vector_type(4))) int   int4v;

__device__ inline unsigned short f2bf_bits(float f) {
    union { float f; unsigned u; } v; v.f = f;
    unsigned r = (v.u + 0x7FFFu + ((v.u >> 16) & 1u)) >> 16;
    return (unsigned short)r;
}

__device__ inline float sigmoid_fast(float x) {
    return 1.f / (1.f + __expf(-x));
}

__device__ inline float tanh_fast(float x) {
    float a = fabsf(x);
    float e = __expf(-2.f * a);
    float r = (1.f - e) / (1.f + e);
    return copysignf(r, x);
}

__device__ inline short4v pack_bf4(float4v v) {
    short4v o;
    o[0] = (short)f2bf_bits(v[0]);
    o[1] = (short)f2bf_bits(v[1]);
    o[2] = (short)f2bf_bits(v[2]);
    o[3] = (short)f2bf_bits(v[3]);
    return o;
}

union Frag { int i[4]; int4v i4; short8 s8; };

__global__ __launch_bounds__(512) void lstm_persistent(
    const float* __restrict__ x, const float* __restrict__ Wx,
    const float* __restrict__ Wh, const float* __restrict__ bias,
    float* __restrict__ out, unsigned int* __restrict__ flags)
{
    const int tid  = threadIdx.x;
    const int lane = tid & 63;
    const int wave = tid >> 6;      // 8 waves
    const int ms   = wave & 3;      // M-strip (16 rows) within 64-batch tile
    const int nt   = wave >> 2;     // N-tile (16 cols) within 32 cols
    const int ct   = blockIdx.x & 63;   // column tile: hidden units ct*8..+7
    const int bt   = blockIdx.x >> 6;   // batch tile: batches bt*64..+63
    const int jh0  = ct * 8;

    __shared__ float zls[64 * 33];          // z tile, padded
    __shared__ float cls[64 * 8];           // c state
    __shared__ float bls[32];               // bias slice
    __shared__ unsigned short xls[2][64 * XROW];  // double-buffered x_t (bf16)
    __shared__ __align__(16) char exls[4 * 16 * 64 * 16];  // h A-frag exchange

    for (int i = tid; i < 64 * 8; i += 512) cls[i] = 0.f;
    if (tid < 32) bls[tid] = bias[(tid >> 3) * 512 + jh0 + (tid & 7)];

    // ---- register-resident weight B-frags: ks 0..7 = Wx, ks 8..23 = Wh ----
    const int l15 = lane & 15;
    const int l4  = lane >> 4;
    const int ncol = nt * 16 + l15;
    const int col  = (ncol >> 3) * 512 + jh0 + (ncol & 7);
    short8 wfrag[KX + KH];
#pragma unroll
    for (int ks = 0; ks < KX + KH; ++ks) {
        short8 w;
#pragma unroll
        for (int j = 0; j < 8; ++j) {
            int k = ks * 32 + l4 * 8 + j;
            float v = (k < D_) ? Wx[(size_t)k * G4_ + col]
                               : Wh[(size_t)(k - D_) * G4_ + col];
            w[j] = (short)f2bf_bits(v);
        }
        wfrag[ks] = w;
    }

    // x staging mapping: 16 row-groups of 32 lanes, 512B-contiguous chunks
    const int srow = tid >> 5;          // 0..15
    const int scol = (tid & 31) * 4;    // 0,4,..,124
    const float* xbase = x + (size_t)(bt * 64) * (T_ * D_);

    // A-frag row (h and x): m = ms*16 + l15
    const int mrow = ms * 16 + l15;
    const int gb_a = bt * 64 + mrow;

    // h-plane consumer base: row gb_a of out, own half ks = nt*8 + j
    // addr(t, j) = out + gb_a*T*H + (t-1)*H + (nt*8+j)*32 + l4*8
    const float* const hsrc =
        out + (size_t)gb_a * (T_ * H_) + (nt * 8) * 32 + l4 * 8;
    const int own0 = nt * 8;            // own half first ks
    const int twn0 = (nt ^ 1) * 8;      // twin half first ks

    // gate-phase mapping
    const int bl = tid >> 3, ug = tid & 7;
    const int gb_g = bt * 64 + bl;

    unsigned int* myflag = flags + bt * 64 + lane;

    // ---- prologue: stage x_0, x-part acc for t=0, prefetch x_1 (packed) ----
    short4v rxp[8];
#pragma unroll
    for (int r = 0; r < 4; ++r) {
        const float* xp = xbase + (size_t)(r * 16 + srow) * (T_ * D_);
        int row = r * 16 + srow;
        *(short4v*)(&xls[0][row * XROW + scol]) =
            pack_bf4(*(const float4v*)(xp + scol));
        *(short4v*)(&xls[0][row * XROW + scol + 128]) =
            pack_bf4(*(const float4v*)(xp + scol + 128));
    }
    __syncthreads();
    float4v accx = {0.f, 0.f, 0.f, 0.f};
#pragma unroll
    for (int ks = 0; ks < KX; ++ks) {
        short8 a = *(const short8*)(&xls[0][mrow * XROW + ks * 32 + l4 * 8]);
        accx = __builtin_amdgcn_mfma_f32_16x16x32_bf16(a, wfrag[ks], accx, 0, 0, 0);
    }
#pragma unroll
    for (int r = 0; r < 4; ++r) {
        const float* xp = xbase + (size_t)(r * 16 + srow) * (T_ * D_) + D_;
        rxp[r * 2]     = pack_bf4(*(const float4v*)(xp + scol));
        rxp[r * 2 + 1] = pack_bf4(*(const float4v*)(xp + scol + 128));
    }

    // ---- ONE-TIME acquire fence: invalidate pre-run L2/L1 relics over the
    //      exchange planes (harness reset()/verify may have cached or
    //      dirtied `out` lines on any XCD). Once per kernel, off-loop. ----
    __builtin_amdgcn_fence(__ATOMIC_ACQUIRE, "agent");

    for (int t = 0; t < T_; ++t) {
        // ---- (A) commit prefetched x_{t+1} into the other LDS buffer ----
        if (t + 1 < T_) {
            unsigned short* xb = xls[(t + 1) & 1];
#pragma unroll
            for (int r = 0; r < 4; ++r) {
                int row = r * 16 + srow;
                *(short4v*)(xb + row * XROW + scol)       = rxp[r * 2];
                *(short4v*)(xb + row * XROW + scol + 128) = rxp[r * 2 + 1];
            }
        }

        Frag own[8];
        if (t) {
            // ---- (B) per-wave poll: all 64 producers of this bt >= t ----
            {
                const unsigned tgt = (unsigned)t;
                while (true) {
                    unsigned f = __hip_atomic_load(myflag, __ATOMIC_RELAXED,
                                                   __HIP_MEMORY_SCOPE_AGENT);
                    if (__all((int)(f >= tgt))) break;
                }
            }

            // ---- (C) own-half h loads from out plane t-1 (sc0: L1-bypass,
            //          L2-cached -> cross-block reuse within the XCD) ----
            float4v hf[16];
            {
                const float* hp = hsrc + (size_t)(t - 1) * H_;
#pragma unroll
                for (int j = 0; j < 8; ++j) {
                    asm volatile("global_load_dwordx4 %0, %1, off sc0"
                                 : "=v"(hf[2 * j])     : "v"(hp + j * 32));
                    asm volatile("global_load_dwordx4 %0, %1, off sc0"
                                 : "=v"(hf[2 * j + 1]) : "v"(hp + j * 32 + 4));
                }
            }
            asm volatile("s_waitcnt vmcnt(0)" ::: "memory");
            __builtin_amdgcn_sched_barrier(0);

            // ---- (D) cvt_pk to bf16 A-frags + LDS exchange write ----
#pragma unroll
            for (int j = 0; j < 8; ++j) {
                Frag fr;
                asm("v_cvt_pk_bf16_f32 %0, %1, %2"
                    : "=v"(fr.i[0]) : "v"(hf[2 * j][0]), "v"(hf[2 * j][1]));
                asm("v_cvt_pk_bf16_f32 %0, %1, %2"
                    : "=v"(fr.i[1]) : "v"(hf[2 * j][2]), "v"(hf[2 * j][3]));
                asm("v_cvt_pk_bf16_f32 %0, %1, %2"
                    : "=v"(fr.i[2]) : "v"(hf[2 * j + 1][0]), "v"(hf[2 * j + 1][1]));
                asm("v_cvt_pk_bf16_f32 %0, %1, %2"
                    : "=v"(fr.i[3]) : "v"(hf[2 * j + 1][2]), "v"(hf[2 * j + 1][3]));
                own[j] = fr;
                *(int4v*)(exls + (((ms * 16) + (own0 + j)) * 64 + lane) * 16) =
                    fr.i4;
            }
            __syncthreads();   // (E) twins exchanged
        }

        // ---- (F) h-part MFMAs (own half from regs, twin half from LDS) ----
        float4v zsum = accx;
        if (t) {
            __builtin_amdgcn_s_setprio(1);
#pragma unroll
            for (int j = 0; j < 8; ++j)
                zsum = __builtin_amdgcn_mfma_f32_16x16x32_bf16(
                           own[j].s8, wfrag[KX + own0 + j], zsum, 0, 0, 0);
#pragma unroll
            for (int j = 0; j < 8; ++j) {
                Frag f;
                f.i4 = *(const int4v*)(
                    exls + (((ms * 16) + (twn0 + j)) * 64 + lane) * 16);
                zsum = __builtin_amdgcn_mfma_f32_16x16x32_bf16(
                           f.s8, wfrag[KX + twn0 + j], zsum, 0, 0, 0);
            }
            __builtin_amdgcn_s_setprio(0);
        }
        // D layout: D[row=(lane>>4)*4+r][col=lane&15]
#pragma unroll
        for (int r = 0; r < 4; ++r) {
            int row = ms * 16 + l4 * 4 + r;
            zls[row * 33 + nt * 16 + l15] = zsum[r];
        }
        __syncthreads();

        // ---- (G) gates + h-publish = out store (sc0 sc1 write-through) ----
        {
            float zi = zls[bl * 33 + ug]      + bls[ug];
            float zf = zls[bl * 33 + 8 + ug]  + bls[8 + ug];
            float zg = zls[bl * 33 + 16 + ug] + bls[16 + ug];
            float zo = zls[bl * 33 + 24 + ug] + bls[24 + ug];
            float ig = sigmoid_fast(zi);
            float fg = sigmoid_fast(zf);
            float gg = tanh_fast(zg);
            float og = sigmoid_fast(zo);
            float cold = cls[bl * 8 + ug];
            float cnew = fg * cold + ig * gg;
            float hnew = og * tanh_fast(cnew);
            cls[bl * 8 + ug] = cnew;
            const float* opt =
                out + (size_t)gb_g * (T_ * H_) + (size_t)t * H_ + jh0 + ug;
            asm volatile("global_store_dword %0, %1, off sc0 sc1"
                         :: "v"(opt), "v"(hnew) : "memory");
            if (t == T_ - 1) {
                const size_t BTH = (size_t)B_ * T_ * H_;
                out[BTH + (size_t)gb_g * H_ + jh0 + ug] = hnew;
                out[BTH + (size_t)B_ * H_ + (size_t)gb_g * H_ + jh0 + ug] = cnew;
            }
        }
        asm volatile("s_waitcnt vmcnt(0)" ::: "memory");   // plane t ACKed in L3
        __syncthreads();                                   // all waves stored

        // ---- (G2) publish: one relaxed agent store, no RMW chain ----
        if (tid == 0 && t + 1 < T_)
            __hip_atomic_store(flags + bt * 64 + ct, (unsigned)(t + 1),
                               __ATOMIC_RELAXED, __HIP_MEMORY_SCOPE_AGENT);

        // ---- (H) off-path window: x-part MFMAs for t+1, prefetch x_{t+2} ----
        float4v nacc = {0.f, 0.f, 0.f, 0.f};
        if (t + 1 < T_) {
            const unsigned short* xb = xls[(t + 1) & 1];
#pragma unroll
            for (int ks = 0; ks < KX; ++ks) {
                short8 a = *(const short8*)(xb + mrow * XROW + ks * 32 + l4 * 8);
                nacc = __builtin_amdgcn_mfma_f32_16x16x32_bf16(
                           a, wfrag[ks], nacc, 0, 0, 0);
            }
            if (t + 2 < T_) {
#pragma unroll
                for (int r = 0; r < 4; ++r) {
                    const float* xp = xbase + (size_t)(r * 16 + srow) * (T_ * D_)
                                    + (size_t)(t + 2) * D_;
                    rxp[r * 2]     = pack_bf4(*(const float4v*)(xp + scol));
                    rxp[r * 2 + 1] = pack_bf4(*(const float4v*)(xp + scol + 128));
                }
            }
        }
        accx = nacc;
    }
}

extern "C" void kernel_launch(void* const* d_in, const int* in_sizes, int n_in,
                              void* d_out, int out_size, void* d_ws, size_t ws_size,
                              hipStream_t stream) {
    const float* x    = (const float*)d_in[0];
    const float* Wx   = (const float*)d_in[1];
    const float* Wh   = (const float*)d_in[2];
    const float* bias = (const float*)d_in[3];
    float* out = (float*)d_out;

    unsigned int* flags = (unsigned int*)d_ws;   // 128 u32

    hipMemsetAsync(d_ws, 0, 1024, stream);

    lstm_persistent<<<dim3(NBLK), dim3(512), 0, stream>>>(
        x, Wx, Wh, bias, out, flags);
}

// Round 8
// 4255.319 us; speedup vs baseline: 1.3636x; 1.3636x over previous
//
#include <hip/hip_runtime.h>
#include <hip/hip_bf16.h>

// LSTM DynamicRNN: B=128, T=512, D=256, H=512.
// Round 11 = Round-1 base (best measured: 2250 us) + SELF-VALIDATING h
// RECORDS replacing the {h-store, vmcnt(0) ack, flag store, flag poll,
// h load} protocol chain (3 L3 round-trips) with {one fire-and-forget
// 16B record store} -> {consumer spin-validate = detect+load fused}.
//   record = [8B payload (4 bf16 units) | 8B shadow = payload ^ TAG(t)]
//   stored as ONE global_store_dwordx4 sc0 sc1 (16B store not torn;
//   stale/partial states fail the XOR check and spin; stale-data-matching
//   implies data identical -> benign). Zero false accepts.
//   hbuf = 2 parity planes x [ut4=128][row=128] x 16B = 512 KB at FIXED
//   addresses -> L3-resident (R7 taught: sc0sc1 write-through only works
//   when reads keep the lines allocated in L3; rotating planes -> HBM).
//   Overwrite safety (R4-proven induction): P publishes tag t+1 only after
//   validating ALL tag-t records => every producer published t => every
//   producer finished reading plane (t-1)&1 == plane (t+1)&1.
// nt-twin dedup: R1's twin waves loaded IDENTICAL 256B; now each wave
// spins on its 8-ks half (16 records) and twins exchange unpacked A-frags
// via LDS (+1 barrier, +64KB LDS) -> exchange traffic stays at R1's
// 16 MB/step despite the 2x record overhead.
// Everything else (x path, gates, zls, shapes, launch bounds) = R1.

#define B_   128
#define T_   512
#define D_   256
#define H_   512
#define G4_  2048   // 4*H
#define NBLK 128
#define KX   8      // x-part k-steps (K=256)
#define XROW 264    // 256 + 8 pad (shorts) per staged x row
#define TAGK 0x9E3779B97F4A7C15ull
#define PLANE_B (128 * 128 * 16)   // one parity plane: [ut4][row] x 16B

typedef __attribute__((ext_vector_type(8))) short short8;
typedef __attribute__((ext_vector_type(4))) short short4v;
typedef __attribute__((ext_vector_type(4))) float float4v;
typedef __attribute__((ext_vector_type(4))) int   int4v;

__device__ inline unsigned short f2bf_bits(float f) {
    union { float f; unsigned u; } v; v.f = f;
    unsigned r = (v.u + 0x7FFFu + ((v.u >> 16) & 1u)) >> 16;
    return (unsigned short)r;
}

__device__ inline float sigmoid_fast(float x) {
    return 1.f / (1.f + __expf(-x));
}

__device__ inline float tanh_fast(float x) {
    float a = fabsf(x);
    float e = __expf(-2.f * a);
    float r = (1.f - e) / (1.f + e);
    return copysignf(r, x);
}

__device__ inline short4v pack_bf4(float4v v) {
    short4v o;
    o[0] = (short)f2bf_bits(v[0]);
    o[1] = (short)f2bf_bits(v[1]);
    o[2] = (short)f2bf_bits(v[2]);
    o[3] = (short)f2bf_bits(v[3]);
    return o;
}

union Frag { int i[4]; int4v i4; short8 s8; };

// ---- record load / validate macros (all indices compile-time) ----
#define LOADH(H)                                                             \
    {                                                                        \
        _Pragma("unroll")                                                    \
        for (int k_ = (H) * 4; k_ < (H) * 4 + 4; ++k_) {                     \
            const char* p_ = cb + k_ * 16384;                                \
            asm volatile("global_load_dwordx4 %0, %1, off sc0 sc1"           \
                         : "=v"(rec[2 * k_]) : "v"(p_));                     \
            asm volatile("global_load_dwordx4 %0, %1, off offset:2048 sc0 sc1" \
                         : "=v"(rec[2 * k_ + 1]) : "v"(p_));                 \
        }                                                                    \
    }

#define VALIDH(H, okv)                                                       \
    {                                                                        \
        okv = 1;                                                             \
        _Pragma("unroll")                                                    \
        for (int i_ = (H) * 8; i_ < (H) * 8 + 8; ++i_)                       \
            okv &= (int)((((unsigned)(rec[i_][0] ^ rec[i_][2])) == tagLo) &  \
                         (((unsigned)(rec[i_][1] ^ rec[i_][3])) == tagHi));  \
    }

__global__ __launch_bounds__(512, 2) void lstm_persistent(
    const float* __restrict__ x, const float* __restrict__ Wx,
    const float* __restrict__ Wh, const float* __restrict__ bias,
    float* __restrict__ out, char* __restrict__ hbuf)
{
    const int tid  = threadIdx.x;
    const int lane = tid & 63;
    const int wave = tid >> 6;      // 8 waves
    const int ms   = wave & 3;      // M-strip (16 rows) within 64-batch tile
    const int nt   = wave >> 2;     // N-tile (16 cols) within 32 cols
    const int ct   = blockIdx.x & 63;   // column tile: hidden units ct*8..+7
    const int bt   = blockIdx.x >> 6;   // batch tile: batches bt*64..+63
    const int jh0  = ct * 8;

    __shared__ float zls[64 * 33];          // z tile, padded
    __shared__ float cls[64 * 8];           // c state
    __shared__ float bls[32];               // bias slice
    __shared__ __align__(16) unsigned short hls[512];   // h bf16 staging
    __shared__ unsigned short xls[2][64 * XROW];  // double-buffered x_t (bf16)
    __shared__ int4v exls[4 * 16 * 64];     // twin A-frag exchange (64 KB)

    for (int i = tid; i < 64 * 8; i += 512) cls[i] = 0.f;
    if (tid < 32) bls[tid] = bias[(tid >> 3) * 512 + jh0 + (tid & 7)];

    // ---- register-resident weight B-frags: ks 0..7 = Wx, ks 8..23 = Wh ----
    const int l15 = lane & 15;
    const int l4  = lane >> 4;
    const int ncol = nt * 16 + l15;
    const int col  = (ncol >> 3) * 512 + jh0 + (ncol & 7);
    short8 wfrag[KX + 16];
#pragma unroll
    for (int ks = 0; ks < KX + 16; ++ks) {
        short8 w;
#pragma unroll
        for (int j = 0; j < 8; ++j) {
            int k = ks * 32 + l4 * 8 + j;
            float v = (k < D_) ? Wx[(size_t)k * G4_ + col]
                               : Wh[(size_t)(k - D_) * G4_ + col];
            w[j] = (short)f2bf_bits(v);
        }
        wfrag[ks] = w;
    }

    // x staging mapping: 16 row-groups of 32 lanes, 512B-contiguous chunks
    const int srow = tid >> 5;          // 0..15
    const int scol = (tid & 31) * 4;    // 0,4,..,124
    const float* xbase = x + (size_t)(bt * 64) * (T_ * D_);

    // A-frag row (h and x): m = ms*16 + l15
    const int mrow = ms * 16 + l15;
    const int gb_a = bt * 64 + mrow;

    // consumer record base: own ks-half nt*8..+7
    // addr(k,j) = hbuf + plane + (((nt*8+k)*8 + l4*2 + j)*128 + gb_a)*16
    //           = crb + plane + k*16384 + j*2048
    char* const crb = hbuf + ((size_t)(nt * 64 + l4 * 2) * 128 + gb_a) * 16;

    // gate-phase mapping
    const int bl = tid >> 3, ug = tid & 7;
    const int gb_g = bt * 64 + bl;

    // producer record base (tid<128): j=tid&1, r=tid>>1
    char* const prb = hbuf +
        ((size_t)(ct * 2 + (tid & 1)) * 128 + bt * 64 + (tid >> 1)) * 16;

    // ---- prologue: stage x_0, x-part acc for t=0, prefetch x_1 (packed) ----
    short4v rxp[8];
#pragma unroll
    for (int r = 0; r < 4; ++r) {
        const float* xp = xbase + (size_t)(r * 16 + srow) * (T_ * D_);
        int row = r * 16 + srow;
        *(short4v*)(&xls[0][row * XROW + scol]) =
            pack_bf4(*(const float4v*)(xp + scol));
        *(short4v*)(&xls[0][row * XROW + scol + 128]) =
            pack_bf4(*(const float4v*)(xp + scol + 128));
    }
    __syncthreads();
    float4v accx = {0.f, 0.f, 0.f, 0.f};
#pragma unroll
    for (int ks = 0; ks < KX; ++ks) {
        short8 a = *(const short8*)(&xls[0][mrow * XROW + ks * 32 + l4 * 8]);
        accx = __builtin_amdgcn_mfma_f32_16x16x32_bf16(a, wfrag[ks], accx, 0, 0, 0);
    }
#pragma unroll
    for (int r = 0; r < 4; ++r) {
        const float* xp = xbase + (size_t)(r * 16 + srow) * (T_ * D_) + D_;
        rxp[r * 2]     = pack_bf4(*(const float4v*)(xp + scol));
        rxp[r * 2 + 1] = pack_bf4(*(const float4v*)(xp + scol + 128));
    }

    unsigned long long tcur = 0;   // TAGK * t

    for (int t = 0; t < T_; ++t) {
        // ---- (A) commit prefetched x_{t+1} into the other LDS buffer ----
        if (t + 1 < T_) {
            unsigned short* xb = xls[(t + 1) & 1];
#pragma unroll
            for (int r = 0; r < 4; ++r) {
                int row = r * 16 + srow;
                *(short4v*)(xb + row * XROW + scol)       = rxp[r * 2];
                *(short4v*)(xb + row * XROW + scol + 128) = rxp[r * 2 + 1];
            }
        }

        float4v zsum = accx;   // carries the x-part

        if (t) {
            const unsigned tagLo = (unsigned)tcur;
            const unsigned tagHi = (unsigned)(tcur >> 32);
            const char* cb = crb + (size_t)(t & 1) * PLANE_B;
            int4v rec[16];

            // ---- (B) issue own-half record loads (16 x 16B, L2-bypass) ----
            LOADH(0)
            LOADH(1)

            // ---- (C) spin-validate h0 (detect == data arrival) ----
            asm volatile("s_waitcnt vmcnt(8)" ::: "memory");
            __builtin_amdgcn_sched_barrier(0);
            int ok0; VALIDH(0, ok0)
            while (!__all(ok0)) {
                LOADH(0)
                asm volatile("s_waitcnt vmcnt(0)" ::: "memory");
                __builtin_amdgcn_sched_barrier(0);
                VALIDH(0, ok0)
            }
            // unpack -> exls publish -> own MFMAs (overlaps twin's spin)
#pragma unroll
            for (int k = 0; k < 4; ++k) {
                Frag f;
                f.i[0] = rec[2 * k][0];     f.i[1] = rec[2 * k][1];
                f.i[2] = rec[2 * k + 1][0]; f.i[3] = rec[2 * k + 1][1];
                exls[(ms * 16 + nt * 8 + k) * 64 + lane] = f.i4;
                zsum = __builtin_amdgcn_mfma_f32_16x16x32_bf16(
                           f.s8, wfrag[KX + nt * 8 + k], zsum, 0, 0, 0);
            }

            // ---- (D) spin-validate h1 ----
            asm volatile("s_waitcnt vmcnt(0)" ::: "memory");
            __builtin_amdgcn_sched_barrier(0);
            int ok1; VALIDH(1, ok1)
            while (!__all(ok1)) {
                LOADH(1)
                asm volatile("s_waitcnt vmcnt(0)" ::: "memory");
                __builtin_amdgcn_sched_barrier(0);
                VALIDH(1, ok1)
            }
#pragma unroll
            for (int k = 4; k < 8; ++k) {
                Frag f;
                f.i[0] = rec[2 * k][0];     f.i[1] = rec[2 * k][1];
                f.i[2] = rec[2 * k + 1][0]; f.i[3] = rec[2 * k + 1][1];
                exls[(ms * 16 + nt * 8 + k) * 64 + lane] = f.i4;
                zsum = __builtin_amdgcn_mfma_f32_16x16x32_bf16(
                           f.s8, wfrag[KX + nt * 8 + k], zsum, 0, 0, 0);
            }

            __syncthreads();   // (E) twin frags exchanged

            // ---- (F) twin-half MFMAs from LDS ----
#pragma unroll
            for (int k = 0; k < 8; ++k) {
                Frag f;
                f.i4 = exls[(ms * 16 + (nt ^ 1) * 8 + k) * 64 + lane];
                zsum = __builtin_amdgcn_mfma_f32_16x16x32_bf16(
                           f.s8, wfrag[KX + (nt ^ 1) * 8 + k], zsum, 0, 0, 0);
            }
        }

        // D layout: D[row=(lane>>4)*4+r][col=lane&15]
#pragma unroll
        for (int r = 0; r < 4; ++r) {
            int row = ms * 16 + l4 * 4 + r;
            zls[row * 33 + nt * 16 + l15] = zsum[r];
        }
        __syncthreads();

        // ---- (G) gates ----
        {
            float zi = zls[bl * 33 + ug]      + bls[ug];
            float zf = zls[bl * 33 + 8 + ug]  + bls[8 + ug];
            float zg = zls[bl * 33 + 16 + ug] + bls[16 + ug];
            float zo = zls[bl * 33 + 24 + ug] + bls[24 + ug];
            float ig = sigmoid_fast(zi);
            float fg = sigmoid_fast(zf);
            float gg = tanh_fast(zg);
            float og = sigmoid_fast(zo);
            float cold = cls[bl * 8 + ug];
            float cnew = fg * cold + ig * gg;
            float hnew = og * tanh_fast(cnew);
            cls[bl * 8 + ug] = cnew;
            hls[bl * 8 + ug] = f2bf_bits(hnew);
            out[(size_t)gb_g * (T_ * H_) + (size_t)t * H_ + jh0 + ug] = hnew;
            if (t == T_ - 1) {
                const size_t BTH = (size_t)B_ * T_ * H_;
                out[BTH + (size_t)gb_g * H_ + jh0 + ug] = hnew;
                out[BTH + (size_t)B_ * H_ + (size_t)gb_g * H_ + jh0 + ug] = cnew;
            }
        }
        __syncthreads();   // hls ready (also orders zls reuse)

        // ---- (H) publish h_{t+1} records: fire-and-forget, NO ack ----
        if (t + 1 < T_ && tid < 128) {
            const int jr = tid & 1, rr = tid >> 1;
            unsigned long long d =
                *(const unsigned long long*)(&hls[rr * 8 + jr * 4]);
            unsigned long long sh = d ^ (tcur + TAGK);
            int4v st;
            st[0] = (int)(unsigned)d;  st[1] = (int)(unsigned)(d >> 32);
            st[2] = (int)(unsigned)sh; st[3] = (int)(unsigned)(sh >> 32);
            char* p = prb + (size_t)((t + 1) & 1) * PLANE_B;
            asm volatile("global_store_dwordx4 %0, %1, off sc0 sc1"
                         :: "v"(p), "v"(st) : "memory");
        }

        // ---- (I) off-path window: x-part MFMAs for t+1, prefetch x_{t+2} ----
        float4v nacc = {0.f, 0.f, 0.f, 0.f};
        if (t + 1 < T_) {
            const unsigned short* xb = xls[(t + 1) & 1];
#pragma unroll
            for (int ks = 0; ks < KX; ++ks) {
                short8 a = *(const short8*)(xb + mrow * XROW + ks * 32 + l4 * 8);
                nacc = __builtin_amdgcn_mfma_f32_16x16x32_bf16(
                           a, wfrag[ks], nacc, 0, 0, 0);
            }
            if (t + 2 < T_) {
#pragma unroll
                for (int r = 0; r < 4; ++r) {
                    const float* xp = xbase + (size_t)(r * 16 + srow) * (T_ * D_)
                                    + (size_t)(t + 2) * D_;
                    rxp[r * 2]     = pack_bf4(*(const float4v*)(xp + scol));
                    rxp[r * 2 + 1] = pack_bf4(*(const float4v*)(xp + scol + 128));
                }
            }
        }
        accx = nacc;
        tcur += TAGK;
    }
}

extern "C" void kernel_launch(void* const* d_in, const int* in_sizes, int n_in,
                              void* d_out, int out_size, void* d_ws, size_t ws_size,
                              hipStream_t stream) {
    const float* x    = (const float*)d_in[0];
    const float* Wx   = (const float*)d_in[1];
    const float* Wh   = (const float*)d_in[2];
    const float* bias = (const float*)d_in[3];
    float* out = (float*)d_out;

    char* hbuf = (char*)d_ws;   // 2 planes x 256 KB = 512 KB, L3-resident

    hipMemsetAsync(d_ws, 0, (size_t)2 * PLANE_B, stream);

    lstm_persistent<<<dim3(NBLK), dim3(512), 0, stream>>>(
        x, Wx, Wh, bias, out, hbuf);
}

// Round 9
// 4251.395 us; speedup vs baseline: 1.3649x; 1.0009x over previous
//
#include <hip/hip_runtime.h>
#include <hip/hip_bf16.h>

// LSTM DynamicRNN: B=128, T=512, D=256, H=512.
// Round 12 = Round-1 (best measured: 2250 us) + ONE change: nt-twin h-load
// DEDUP. R1's twin waves (same ms, nt=0/1) loaded byte-identical 16 KB of
// h A-fragments from L3 (16 MB/step block-aggregate burst). Now each wave
// loads only its own 8-ks half (8 KB), publishes the frags to LDS (exls),
// one barrier, twin reads the other half from LDS at L2-free speed.
// Halves the L3 burst (16 -> 8 MB/step) to test the burst-BW-stretch
// theory of R1's h phase. Protocol (store -> vmcnt ack -> flag -> poll ->
// load), x path, gates, barriers: byte-identical to R1.
// If dur ~2250 +-3% (null): h phase is protocol/latency-bound, not
// BW-bound -> theory falsified, L3 burst BW is not a limiter.

#define B_   128
#define T_   512
#define D_   256
#define H_   512
#define G4_  2048   // 4*H
#define NBLK 128
#define KH   16     // h-part k-steps (K=512)
#define KX   8      // x-part k-steps (K=256)
#define XROW 264    // 256 + 8 pad (shorts) per staged x row

typedef __attribute__((ext_vector_type(8))) short short8;
typedef __attribute__((ext_vector_type(4))) short short4v;
typedef __attribute__((ext_vector_type(4))) float float4v;
typedef __attribute__((ext_vector_type(4))) int   int4v;

__device__ inline unsigned short f2bf_bits(float f) {
    union { float f; unsigned u; } v; v.f = f;
    unsigned r = (v.u + 0x7FFFu + ((v.u >> 16) & 1u)) >> 16;
    return (unsigned short)r;
}

__device__ inline float sigmoid_fast(float x) {
    return 1.f / (1.f + __expf(-x));
}

__device__ inline float tanh_fast(float x) {
    float a = fabsf(x);
    float e = __expf(-2.f * a);
    float r = (1.f - e) / (1.f + e);
    return copysignf(r, x);
}

__device__ inline short4v pack_bf4(float4v v) {
    short4v o;
    o[0] = (short)f2bf_bits(v[0]);
    o[1] = (short)f2bf_bits(v[1]);
    o[2] = (short)f2bf_bits(v[2]);
    o[3] = (short)f2bf_bits(v[3]);
    return o;
}

union HAu { int4v i4; short8 s8; };

__global__ __launch_bounds__(512, 2) void lstm_persistent(
    const float* __restrict__ x, const float* __restrict__ Wx,
    const float* __restrict__ Wh, const float* __restrict__ bias,
    float* __restrict__ out, unsigned short* __restrict__ hbuf,
    unsigned int* __restrict__ flags)
{
    const int tid  = threadIdx.x;
    const int lane = tid & 63;
    const int wave = tid >> 6;      // 8 waves
    const int ms   = wave & 3;      // M-strip (16 rows) within 64-batch tile
    const int nt   = wave >> 2;     // N-tile (16 cols) within 32 cols
    const int ct   = blockIdx.x & 63;   // column tile: hidden units ct*8..+7
    const int bt   = blockIdx.x >> 6;   // batch tile: batches bt*64..+63
    const int jh0  = ct * 8;

    __shared__ float zls[64 * 33];          // z tile, padded
    __shared__ float cls[64 * 8];           // c state
    __shared__ float bls[32];               // bias slice
    __shared__ unsigned short hls[512];     // h bf16 staging
    __shared__ unsigned short xls[2][64 * XROW];  // double-buffered x_t (bf16)
    __shared__ __align__(16) int4v exls[64 * 64]; // twin A-frag exchange, 64 KB

    for (int i = tid; i < 64 * 8; i += 512) cls[i] = 0.f;
    if (tid < 32) bls[tid] = bias[(tid >> 3) * 512 + jh0 + (tid & 7)];

    // ---- register-resident weight B-frags: ks 0..7 = Wx, ks 8..23 = Wh ----
    const int l15 = lane & 15;
    const int l4  = lane >> 4;
    const int ncol = nt * 16 + l15;
    const int col  = (ncol >> 3) * 512 + jh0 + (ncol & 7);
    short8 wfrag[KX + KH];
#pragma unroll
    for (int ks = 0; ks < KX + KH; ++ks) {
        short8 w;
#pragma unroll
        for (int j = 0; j < 8; ++j) {
            int k = ks * 32 + l4 * 8 + j;
            float v = (k < D_) ? Wx[(size_t)k * G4_ + col]
                               : Wh[(size_t)(k - D_) * G4_ + col];
            w[j] = (short)f2bf_bits(v);
        }
        wfrag[ks] = w;
    }

    // x staging mapping: 16 row-groups of 32 lanes, 512B-contiguous chunks
    const int srow = tid >> 5;          // 0..15
    const int scol = (tid & 31) * 4;    // 0,4,..,124
    const float* xbase = x + (size_t)(bt * 64) * (T_ * D_);

    // A-frag row (h and x): m = ms*16 + l15
    const int mrow = ms * 16 + l15;
    const int gb_a = bt * 64 + mrow;

    // gate-phase mapping
    const int bl = tid >> 3, ug = tid & 7;
    const int gb_g = bt * 64 + bl;

    unsigned int* myflag = flags + bt * 64 + lane;

    // own ks-half: global ks = nt*8 + k, unit-group ut = ks*4 + l4
    const int ks0 = nt * 8;             // own half first ks
    const int kt0 = (nt ^ 1) * 8;       // twin half first ks

    // ---- prologue: stage x_0, x-part acc for t=0, prefetch x_1 (packed) ----
    short4v rxp[8];
#pragma unroll
    for (int r = 0; r < 4; ++r) {
        const float* xp = xbase + (size_t)(r * 16 + srow) * (T_ * D_);
        int row = r * 16 + srow;
        *(short4v*)(&xls[0][row * XROW + scol]) =
            pack_bf4(*(const float4v*)(xp + scol));
        *(short4v*)(&xls[0][row * XROW + scol + 128]) =
            pack_bf4(*(const float4v*)(xp + scol + 128));
    }
    __syncthreads();
    float4v accx = {0.f, 0.f, 0.f, 0.f};
#pragma unroll
    for (int ks = 0; ks < KX; ++ks) {
        short8 a = *(const short8*)(&xls[0][mrow * XROW + ks * 32 + l4 * 8]);
        accx = __builtin_amdgcn_mfma_f32_16x16x32_bf16(a, wfrag[ks], accx, 0, 0, 0);
    }
#pragma unroll
    for (int r = 0; r < 4; ++r) {
        const float* xp = xbase + (size_t)(r * 16 + srow) * (T_ * D_) + D_;
        rxp[r * 2]     = pack_bf4(*(const float4v*)(xp + scol));
        rxp[r * 2 + 1] = pack_bf4(*(const float4v*)(xp + scol + 128));
    }

    int cur = 0;
    for (int t = 0; t < T_; ++t) {
        // ---- (A) commit prefetched x_{t+1} into the other LDS buffer ----
        if (t + 1 < T_) {
            unsigned short* xb = xls[(t + 1) & 1];
#pragma unroll
            for (int r = 0; r < 4; ++r) {
                int row = r * 16 + srow;
                *(short4v*)(xb + row * XROW + scol)       = rxp[r * 2];
                *(short4v*)(xb + row * XROW + scol + 128) = rxp[r * 2 + 1];
            }
        }

        // ---- (B) per-wave poll: all 64 producers of this bt at step >= t ----
        if (t) {
            const unsigned tgt = (unsigned)t;
            while (true) {
                unsigned f = __hip_atomic_load(myflag, __ATOMIC_RELAXED,
                                               __HIP_MEMORY_SCOPE_AGENT);
                if (__all((int)(f >= tgt))) break;
            }
        }

        // ---- (C) coherent h_t loads: OWN 8-ks half only (dedup) ----
        HAu ha[8];
        {
            const unsigned short* hb0 =
                hbuf + ((size_t)(cur * 64 + ks0 * 4 + l4) * 128 + gb_a) * 8;
#pragma unroll
            for (int k = 0; k < 8; ++k) {
                const unsigned short* ap = hb0 + (size_t)k * (4 * 128 * 8);
                asm volatile("global_load_dwordx4 %0, %1, off sc0 sc1"
                             : "=v"(ha[k].i4) : "v"(ap));
            }
        }

        // ---- (D) own-half MFMAs (2 phases) + exls publish ----
        float4v a0 = accx;                    // carries the x-part
        float4v a1 = {0.f, 0.f, 0.f, 0.f};
        asm volatile("s_waitcnt vmcnt(4)" ::: "memory");   // 4 oldest done
        __builtin_amdgcn_sched_barrier(0);
#pragma unroll
        for (int k = 0; k < 4; ++k) {
            exls[(ms * 16 + ks0 + k) * 64 + lane] = ha[k].i4;
            a0 = __builtin_amdgcn_mfma_f32_16x16x32_bf16(
                     ha[k].s8, wfrag[KX + ks0 + k], a0, 0, 0, 0);
        }
        asm volatile("s_waitcnt vmcnt(0)" ::: "memory");
        __builtin_amdgcn_sched_barrier(0);
#pragma unroll
        for (int k = 4; k < 8; ++k) {
            exls[(ms * 16 + ks0 + k) * 64 + lane] = ha[k].i4;
            a1 = __builtin_amdgcn_mfma_f32_16x16x32_bf16(
                     ha[k].s8, wfrag[KX + ks0 + k], a1, 0, 0, 0);
        }
        __syncthreads();   // (D2) twin frags exchanged

        // ---- (E) twin-half MFMAs from LDS ----
#pragma unroll
        for (int k = 0; k < 4; ++k) {
            HAu f;
            f.i4 = exls[(ms * 16 + kt0 + k) * 64 + lane];
            a0 = __builtin_amdgcn_mfma_f32_16x16x32_bf16(
                     f.s8, wfrag[KX + kt0 + k], a0, 0, 0, 0);
        }
#pragma unroll
        for (int k = 4; k < 8; ++k) {
            HAu f;
            f.i4 = exls[(ms * 16 + kt0 + k) * 64 + lane];
            a1 = __builtin_amdgcn_mfma_f32_16x16x32_bf16(
                     f.s8, wfrag[KX + kt0 + k], a1, 0, 0, 0);
        }
        // D layout: D[row=(lane>>4)*4+r][col=lane&15]
#pragma unroll
        for (int r = 0; r < 4; ++r) {
            int row = ms * 16 + l4 * 4 + r;
            zls[row * 33 + nt * 16 + l15] = a0[r] + a1[r];
        }
        __syncthreads();

        // ---- (F) gates + direct coherent h store (coalesced shorts) ----
        {
            float zi = zls[bl * 33 + ug]      + bls[ug];
            float zf = zls[bl * 33 + 8 + ug]  + bls[8 + ug];
            float zg = zls[bl * 33 + 16 + ug] + bls[16 + ug];
            float zo = zls[bl * 33 + 24 + ug] + bls[24 + ug];
            float ig = sigmoid_fast(zi);
            float fg = sigmoid_fast(zf);
            float gg = tanh_fast(zg);
            float og = sigmoid_fast(zo);
            float cold = cls[bl * 8 + ug];
            float cnew = fg * cold + ig * gg;
            float hnew = og * tanh_fast(cnew);
            cls[bl * 8 + ug] = cnew;
            unsigned hv = (unsigned)f2bf_bits(hnew);
            unsigned short* hp = hbuf
                + ((size_t)(((t + 1) & 1) * 64 + ct) * 128 + gb_g) * 8 + ug;
            asm volatile("global_store_short %0, %1, off sc0 sc1"
                         :: "v"(hp), "v"(hv) : "memory");
            out[(size_t)gb_g * (T_ * H_) + (size_t)t * H_ + jh0 + ug] = hnew;
            if (t == T_ - 1) {
                const size_t BTH = (size_t)B_ * T_ * H_;
                out[BTH + (size_t)gb_g * H_ + jh0 + ug] = hnew;
                out[BTH + (size_t)B_ * H_ + (size_t)gb_g * H_ + jh0 + ug] = cnew;
            }
        }
        asm volatile("s_waitcnt vmcnt(0)" ::: "memory");   // h-slice ACKed
        __syncthreads();                                   // all waves stored

        // ---- (G) publish: one relaxed agent store, no RMW chain ----
        if (tid == 0)
            __hip_atomic_store(flags + bt * 64 + ct, (unsigned)(t + 1),
                               __ATOMIC_RELAXED, __HIP_MEMORY_SCOPE_AGENT);

        // ---- (H) off-path window: x-part MFMAs for t+1, prefetch x_{t+2} ----
        float4v nacc = {0.f, 0.f, 0.f, 0.f};
        if (t + 1 < T_) {
            const unsigned short* xb = xls[(t + 1) & 1];
#pragma unroll
            for (int ks = 0; ks < KX; ++ks) {
                short8 a = *(const short8*)(xb + mrow * XROW + ks * 32 + l4 * 8);
                nacc = __builtin_amdgcn_mfma_f32_16x16x32_bf16(
                           a, wfrag[ks], nacc, 0, 0, 0);
            }
            if (t + 2 < T_) {
#pragma unroll
                for (int r = 0; r < 4; ++r) {
                    const float* xp = xbase + (size_t)(r * 16 + srow) * (T_ * D_)
                                    + (size_t)(t + 2) * D_;
                    rxp[r * 2]     = pack_bf4(*(const float4v*)(xp + scol));
                    rxp[r * 2 + 1] = pack_bf4(*(const float4v*)(xp + scol + 128));
                }
            }
        }
        accx = nacc;
        cur ^= 1;
    }
}

extern "C" void kernel_launch(void* const* d_in, const int* in_sizes, int n_in,
                              void* d_out, int out_size, void* d_ws, size_t ws_size,
                              hipStream_t stream) {
    const float* x    = (const float*)d_in[0];
    const float* Wx   = (const float*)d_in[1];
    const float* Wh   = (const float*)d_in[2];
    const float* bias = (const float*)d_in[3];
    float* out = (float*)d_out;

    unsigned short* hbuf = (unsigned short*)d_ws;  // 2x[64][128][8] bf16
    const size_t hbuf_bytes = (size_t)2 * 64 * 128 * 8 * sizeof(unsigned short);
    unsigned int* flags = (unsigned int*)((char*)d_ws + hbuf_bytes);  // 128 u32

    hipMemsetAsync(d_ws, 0, hbuf_bytes + 1024, stream);

    lstm_persistent<<<dim3(NBLK), dim3(512), 0, stream>>>(
        x, Wx, Wh, bias, out, hbuf, flags);
}